// Round 6
// baseline (993.547 us; speedup 1.0000x reference)
//
#include <hip/hip_runtime.h>
#include <hip/hip_cooperative_groups.h>
#include <cstdint>
#include <cstddef>

namespace cg = cooperative_groups;

constexpr int kN = 50000;
constexpr float kSlope = 0.2f;
constexpr float kBnEps = 1e-5f;

static inline int ceil_div(int a, int b) { return (a + b - 1) / b; }

typedef __attribute__((ext_vector_type(8))) _Float16 half8;
typedef __attribute__((ext_vector_type(8))) unsigned short ushortx8;
typedef __attribute__((ext_vector_type(4))) float f32x4;

__device__ inline unsigned short f2h_us(float f) {
  _Float16 h = (_Float16)f;
  return *(unsigned short*)&h;
}

// async global->LDS, 16B per lane, dest = wave-uniform base + lane*16
__device__ inline void gload16(const void* g, void* l) {
  __builtin_amdgcn_global_load_lds((const __attribute__((address_space(1))) unsigned int*)g,
                                   (__attribute__((address_space(3))) unsigned int*)l, 16, 0, 0);
}

// ---------------- fused build: zero + prep + degree + scan + scatter (cooperative) -------
// Replaces 6 CSR kernels + memset + prep (8 dispatches) with ONE cooperative launch.
// Grid 1024x256 (<=2048-block co-residency cap); all phases grid-stride.

__global__ void k_build(const int* __restrict__ src, const int* __restrict__ dst,
                        int* __restrict__ rp, int* __restrict__ deg, int* __restrict__ cur,
                        int* __restrict__ bsum, int* __restrict__ csr, int E, int n,
                        const float* __restrict__ x, unsigned short* __restrict__ x16,
                        const float* __restrict__ W0, unsigned short* __restrict__ Wt0,
                        const float* __restrict__ W1, unsigned short* __restrict__ Wt1,
                        const float* __restrict__ W2, unsigned short* __restrict__ Wt2) {
  cg::grid_group grid = cg::this_grid();
  const int tid = blockIdx.x * blockDim.x + threadIdx.x;
  const int nthr = gridDim.x * blockDim.x;
  __shared__ int sm[256];

  // phase 0: zero counters + prep (cast x -> f16, transpose weights)
  for (int i = tid; i < n; i += nthr) {
    deg[i] = 0;
    cur[i] = 0;
  }
  {
    const int N4 = kN * 64;  // float4 units of x
    const int S0 = 256 * 256, S1 = 256 * 256, S2 = 128 * 256;
    const int total = N4 + S0 + S1 + S2;
    for (int i = tid; i < total; i += nthr) {
      if (i < N4) {
        float4 v = ((const float4*)x)[i];
        ushort4 o;
        o.x = f2h_us(v.x);
        o.y = f2h_us(v.y);
        o.z = f2h_us(v.z);
        o.w = f2h_us(v.w);
        ((ushort4*)x16)[i] = o;
      } else {
        int j = i - N4;
        if (j < S0) {
          int nc = j >> 8, k = j & 255;
          Wt0[j] = f2h_us(W0[(size_t)k * 256 + nc]);
        } else if (j < S0 + S1) {
          int t = j - S0;
          int nc = t >> 8, k = t & 255;
          Wt1[t] = f2h_us(W1[(size_t)k * 256 + nc]);
        } else {
          int t = j - S0 - S1;
          int nc = t >> 8, k = t & 255;
          Wt2[t] = (nc < 40) ? f2h_us(W2[(size_t)k * 40 + nc]) : (unsigned short)0;
        }
      }
    }
  }
  grid.sync();

  // phase 1: degree histogram
  for (int e = tid; e < E; e += nthr) atomicAdd(&deg[dst[e]], 1);
  grid.sync();

  // phase 2: per-chunk (256-wide) inclusive scan into rp[i+1], chunk totals into bsum
  const int nchunks = (n + 255) / 256;  // 196 for n=50000
  for (int c = blockIdx.x; c < nchunks; c += gridDim.x) {
    int i = c * 256 + threadIdx.x;
    int v = (i < n) ? deg[i] : 0;
    sm[threadIdx.x] = v;
    __syncthreads();
    for (int off = 1; off < 256; off <<= 1) {
      int t = (threadIdx.x >= off) ? sm[threadIdx.x - off] : 0;
      __syncthreads();
      sm[threadIdx.x] += t;
      __syncthreads();
    }
    if (i < n) rp[i + 1] = sm[threadIdx.x];
    if (threadIdx.x == 255) bsum[c] = sm[255];
    __syncthreads();
  }
  grid.sync();

  // phase 3: exclusive scan of bsum (nchunks <= 256) on block 0
  if (blockIdx.x == 0) {
    int v = (threadIdx.x < nchunks) ? bsum[threadIdx.x] : 0;
    sm[threadIdx.x] = v;
    __syncthreads();
    for (int off = 1; off < 256; off <<= 1) {
      int t = (threadIdx.x >= off) ? sm[threadIdx.x - off] : 0;
      __syncthreads();
      sm[threadIdx.x] += t;
      __syncthreads();
    }
    if (threadIdx.x < nchunks) bsum[threadIdx.x] = sm[threadIdx.x] - v;  // exclusive
  }
  grid.sync();

  // phase 4: add chunk offsets
  for (int c = blockIdx.x; c < nchunks; c += gridDim.x) {
    int i = c * 256 + threadIdx.x;
    if (i < n) rp[i + 1] += bsum[c];
  }
  if (tid == 0) rp[0] = 0;
  grid.sync();

  // phase 5: scatter edges into CSR
  for (int e = tid; e < E; e += nthr) {
    int d = dst[e];
    int pos = rp[d] + atomicAdd(&cur[d], 1);
    csr[pos] = src[e];
  }
}

// ---------------- f16 MFMA GEMM, global_load_lds staging, fused attn projection ----------
// Single-buffered (R2 structure); dbuf variant was within noise, keep the simpler one.

__global__ __launch_bounds__(256) void k_mfma_gemm(
    const unsigned short* __restrict__ A, const unsigned short* __restrict__ Bt,
    unsigned short* __restrict__ C, const float* __restrict__ asrc,
    const float* __restrict__ adst, float* __restrict__ a_s, float* __restrict__ a_d, int M,
    int K, int Nc, int ldc, int heads, int acols) {
  constexpr int BM = 128, BK = 32;
  // linear [BM][BK] halves: fragment read (wm+i*16+l16)*BK + quad*8 covers a contiguous
  // 1KB region per wave -> zero bank conflicts (measured), matches gload_lds landing.
  __shared__ unsigned short As[BM * BK];
  __shared__ unsigned short Bs[BM * BK];
  int tid = threadIdx.x;
  int wave = tid >> 6, lane = tid & 63;
  int quad = lane >> 4, l16 = lane & 15;
  int wm = (wave & 1) * 64, wn = (wave >> 1) * 64;
  int bm = blockIdx.x * BM, bn = blockIdx.y * BM;
  // staging coords: chunk = 16 rows x 64B = 1KB per instruction
  int srow = lane >> 2;   // 0..15 row within chunk
  int spart = lane & 3;   // 16B part within 64B row
  f32x4 acc[4][4] = {};
  for (int k0 = 0; k0 < K; k0 += BK) {
#pragma unroll
    for (int it = 0; it < 2; it++) {
      int chunk = wave * 2 + it;          // 0..7
      int row = chunk * 16 + srow;        // 0..127
      // NOTE: no M-guard on A reads: last block's stray rows land in adjacent
      // workspace buffers (x16/act16 are followed by other allocations); all
      // result writes are guarded by row < M.
      gload16(A + (size_t)(bm + row) * K + k0 + spart * 8, As + chunk * 512);
      gload16(Bt + (size_t)(bn + row) * K + k0 + spart * 8, Bs + chunk * 512);
    }
    __syncthreads();
    half8 af[4], bf[4];
#pragma unroll
    for (int i = 0; i < 4; i++) {
      af[i] = *(const half8*)(As + (wm + i * 16 + l16) * BK + quad * 8);
      bf[i] = *(const half8*)(Bs + (wn + i * 16 + l16) * BK + quad * 8);
    }
#pragma unroll
    for (int i = 0; i < 4; i++)
#pragma unroll
      for (int j = 0; j < 4; j++)
        acc[i][j] = __builtin_amdgcn_mfma_f32_16x16x32_f16(af[i], bf[j], acc[i][j], 0, 0, 0);
    __syncthreads();
  }
  // C write (f16)
#pragma unroll
  for (int i = 0; i < 4; i++) {
#pragma unroll
    for (int j = 0; j < 4; j++) {
      int col = bn + wn + j * 16 + l16;
      if (col >= Nc) continue;
#pragma unroll
      for (int r = 0; r < 4; r++) {
        int row = bm + wm + i * 16 + quad * 4 + r;
        if (row < M) C[(size_t)row * ldc + col] = f2h_us(acc[i][j][r]);
      }
    }
  }
  // fused attention projection epilogue
  int ghead = (bn + wn) >> 6;
  if (ghead < heads) {
    float asv[4], adv[4];
#pragma unroll
    for (int j = 0; j < 4; j++) {
      int col = bn + wn + j * 16 + l16;
      bool ok = col < acols;
      asv[j] = ok ? asrc[col] : 0.f;
      adv[j] = ok ? adst[col] : 0.f;
    }
#pragma unroll
    for (int i = 0; i < 4; i++) {
#pragma unroll
      for (int r = 0; r < 4; r++) {
        float s = acc[i][0][r] * asv[0] + acc[i][1][r] * asv[1] + acc[i][2][r] * asv[2] +
                  acc[i][3][r] * asv[3];
        float d = acc[i][0][r] * adv[0] + acc[i][1][r] * adv[1] + acc[i][2][r] * adv[2] +
                  acc[i][3][r] * adv[3];
#pragma unroll
        for (int mask = 1; mask <= 8; mask <<= 1) {
          s += __shfl_xor(s, mask, 64);
          d += __shfl_xor(d, mask, 64);
        }
        if (l16 == 0) {
          int row = bm + wm + i * 16 + quad * 4 + r;
          if (row < M) {
            a_s[row * heads + ghead] = s;
            a_d[row * heads + ghead] = d;
          }
        }
      }
    }
  }
}

// ---------------- fused softmax+aggregation: wave per node, 256 ch, f16 h ----------------
// R0 structure — FROZEN. Survived 4 restructurings (R1 deep+pin: spills; R2
// predicated: +80% slots; R5 channel-split: VALU-bound +L2-miss-dominated).
// ~69.5us at FETCH 208MB is the local optimum for this layout.

__global__ __launch_bounds__(256) void k_attn_agg256(
    const int* __restrict__ rp, const int* __restrict__ csr, const _Float16* __restrict__ h,
    const float* __restrict__ a_s, const float* __restrict__ a_d, const float* __restrict__ bias,
    const float* __restrict__ bg, const float* __restrict__ bb, const float* __restrict__ bm,
    const float* __restrict__ bv, unsigned short* __restrict__ out, int n_nodes) {
  int wid = (blockIdx.x * blockDim.x + threadIdx.x) >> 6;
  int lane = threadIdx.x & 63;
  if (wid >= n_nodes) return;
  int n = wid;
  int beg = rp[n], end = rp[n + 1];
  int half = lane >> 5, l32 = lane & 31;
  int head = l32 >> 3;  // 8 lanes x 8 ch per head
  int c = l32 * 8;
  float ad = a_d[n * 4 + head];
  float acc[8] = {};
  float psum = 0.f;
  int e = beg;
  for (; e + 8 <= end; e += 8) {
    int s0 = csr[e + half];
    int s1 = csr[e + 2 + half];
    int s2 = csr[e + 4 + half];
    int s3 = csr[e + 6 + half];
    float x0 = a_s[s0 * 4 + head] + ad;
    float x1 = a_s[s1 * 4 + head] + ad;
    float x2 = a_s[s2 * 4 + head] + ad;
    float x3 = a_s[s3 * 4 + head] + ad;
    half8 v0 = *(const half8*)(h + (size_t)s0 * 256 + c);
    half8 v1 = *(const half8*)(h + (size_t)s1 * 256 + c);
    half8 v2 = *(const half8*)(h + (size_t)s2 * 256 + c);
    half8 v3 = *(const half8*)(h + (size_t)s3 * 256 + c);
    x0 = x0 > 0.f ? x0 : x0 * kSlope;
    x1 = x1 > 0.f ? x1 : x1 * kSlope;
    x2 = x2 > 0.f ? x2 : x2 * kSlope;
    x3 = x3 > 0.f ? x3 : x3 * kSlope;
    float p0 = __expf(x0), p1 = __expf(x1);
    float p2 = __expf(x2), p3 = __expf(x3);
    psum += (p0 + p1) + (p2 + p3);
#pragma unroll
    for (int j = 0; j < 8; j++) {
      acc[j] += (float)v0[j] * p0 + (float)v1[j] * p1;
      acc[j] += (float)v2[j] * p2 + (float)v3[j] * p3;
    }
  }
  for (; e + 2 <= end; e += 2) {
    int s0 = csr[e + half];
    float x0 = a_s[s0 * 4 + head] + ad;
    x0 = x0 > 0.f ? x0 : x0 * kSlope;
    float p0 = __expf(x0);
    psum += p0;
    half8 v0 = *(const half8*)(h + (size_t)s0 * 256 + c);
#pragma unroll
    for (int j = 0; j < 8; j++) acc[j] += (float)v0[j] * p0;
  }
  if (e < end && half == 0) {
    int s0 = csr[e];
    float x0 = a_s[s0 * 4 + head] + ad;
    x0 = x0 > 0.f ? x0 : x0 * kSlope;
    float p0 = __expf(x0);
    psum += p0;
    half8 v0 = *(const half8*)(h + (size_t)s0 * 256 + c);
#pragma unroll
    for (int j = 0; j < 8; j++) acc[j] += (float)v0[j] * p0;
  }
  psum += __shfl_xor(psum, 32, 64);
#pragma unroll
  for (int j = 0; j < 8; j++) acc[j] += __shfl_xor(acc[j], 32, 64);
  if (half == 0) {
    float rden = 1.f / (psum + 1e-16f);
    ushortx8 o;
#pragma unroll
    for (int j = 0; j < 8; j++) {
      float v = acc[j] * rden + bias[c + j];
      v = bg[c + j] * (v - bm[c + j]) * rsqrtf(bv[c + j] + kBnEps) + bb[c + j];
      v = v > 0.f ? v : (__expf(v) - 1.f);  // ELU
      o[j] = f2h_us(v);
    }
    *(ushortx8*)(out + (size_t)n * 256 + c) = o;
  }
}

// ---------------- fused softmax+aggregation: wave per node, 40 ch (packed, stride 40) ----

__global__ __launch_bounds__(256) void k_attn_agg40(
    const int* __restrict__ rp, const int* __restrict__ csr, const _Float16* __restrict__ h,
    const float* __restrict__ a_s, const float* __restrict__ a_d, const float* __restrict__ bias,
    float* __restrict__ out, int n_nodes) {
  int wid = (blockIdx.x * blockDim.x + threadIdx.x) >> 6;
  int lane = threadIdx.x & 63;
  if (wid >= n_nodes) return;
  int n = wid;
  int beg = rp[n], end = rp[n + 1];
  float ad = a_d[n];
  int grp = lane >> 3, l8 = lane & 7;
  int c = l8 * 8;  // valid channels only for l8 < 5
  bool act = l8 < 5;
  float acc[8] = {};
  float psum = 0.f;
  for (int base = beg; base < end; base += 16) {
    int e0 = base + grp;
    int e1 = base + 8 + grp;
    if (e0 < end) {
      int s = csr[e0];
      float x = a_s[s] + ad;
      x = x > 0.f ? x : x * kSlope;
      float p = __expf(x);
      psum += p;
      if (act) {
        half8 hv = *(const half8*)(h + (size_t)s * 40 + c);
#pragma unroll
        for (int j = 0; j < 8; j++) acc[j] += (float)hv[j] * p;
      }
    }
    if (e1 < end) {
      int s = csr[e1];
      float x = a_s[s] + ad;
      x = x > 0.f ? x : x * kSlope;
      float p = __expf(x);
      psum += p;
      if (act) {
        half8 hv = *(const half8*)(h + (size_t)s * 40 + c);
#pragma unroll
        for (int j = 0; j < 8; j++) acc[j] += (float)hv[j] * p;
      }
    }
  }
#pragma unroll
  for (int mask = 8; mask <= 32; mask <<= 1) psum += __shfl_xor(psum, mask, 64);
#pragma unroll
  for (int j = 0; j < 8; j++) {
#pragma unroll
    for (int mask = 8; mask <= 32; mask <<= 1) acc[j] += __shfl_xor(acc[j], mask, 64);
  }
  if (lane < 5) {  // channels 0..39
    float rden = 1.f / (psum + 1e-16f);
    float4 o0, o1;
    o0.x = acc[0] * rden + bias[c + 0];
    o0.y = acc[1] * rden + bias[c + 1];
    o0.z = acc[2] * rden + bias[c + 2];
    o0.w = acc[3] * rden + bias[c + 3];
    o1.x = acc[4] * rden + bias[c + 4];
    o1.y = acc[5] * rden + bias[c + 5];
    o1.z = acc[6] * rden + bias[c + 6];
    o1.w = acc[7] * rden + bias[c + 7];
    *(float4*)(out + (size_t)n * 40 + c) = o0;
    *(float4*)(out + (size_t)n * 40 + c + 4) = o1;
  }
}

// ---------------- driver ----------------

extern "C" void kernel_launch(void* const* d_in, const int* in_sizes, int n_in, void* d_out,
                              int out_size, void* d_ws, size_t ws_size, hipStream_t stream) {
  const float* x = (const float*)d_in[0];
  const int* ei = (const int*)d_in[1];
  const float* W0 = (const float*)d_in[2];
  const float* as0 = (const float*)d_in[3];
  const float* ad0 = (const float*)d_in[4];
  const float* b0 = (const float*)d_in[5];
  const float* bg0 = (const float*)d_in[6];
  const float* bb0 = (const float*)d_in[7];
  const float* bm0 = (const float*)d_in[8];
  const float* bv0 = (const float*)d_in[9];
  const float* W1 = (const float*)d_in[10];
  const float* as1 = (const float*)d_in[11];
  const float* ad1 = (const float*)d_in[12];
  const float* b1 = (const float*)d_in[13];
  const float* bg1 = (const float*)d_in[14];
  const float* bb1 = (const float*)d_in[15];
  const float* bm1 = (const float*)d_in[16];
  const float* bv1 = (const float*)d_in[17];
  const float* W2 = (const float*)d_in[18];
  const float* as2 = (const float*)d_in[19];
  const float* ad2 = (const float*)d_in[20];
  const float* b2 = (const float*)d_in[21];
  float* out = (float*)d_out;

  const int E = in_sizes[1] / 2;
  const int* srcIdx = ei;
  const int* dstIdx = ei + E;

  char* p = (char*)d_ws;
  auto alloc = [&](size_t bytes) -> void* {
    void* r = (void*)p;
    p += (bytes + 255) & ~(size_t)255;
    return r;
  };
  int* rp = (int*)alloc((kN + 1) * sizeof(int));
  int* degcur = (int*)alloc((size_t)2 * kN * sizeof(int));  // deg | cursor
  int* deg = degcur;
  int* cur = degcur + kN;
  int* bsum = (int*)alloc(256 * sizeof(int));
  int* csr = (int*)alloc((size_t)E * sizeof(int));
  float* a_s = (float*)alloc((size_t)kN * 4 * sizeof(float));
  float* a_d = (float*)alloc((size_t)kN * 4 * sizeof(float));
  unsigned short* x16 = (unsigned short*)alloc((size_t)kN * 256 * 2);
  unsigned short* h16 = (unsigned short*)alloc((size_t)kN * 256 * 2);
  unsigned short* act16 = (unsigned short*)alloc((size_t)kN * 256 * 2);
  unsigned short* Wt0 = (unsigned short*)alloc((size_t)256 * 256 * 2);
  unsigned short* Wt1 = (unsigned short*)alloc((size_t)256 * 256 * 2);
  unsigned short* Wt2 = (unsigned short*)alloc((size_t)128 * 256 * 2);

  // fused CSR build + prep: ONE cooperative launch (replaces 8 dispatches)
  {
    int Ee = E, nn = kN;
    void* args[] = {(void*)&srcIdx, (void*)&dstIdx, (void*)&rp,  (void*)&deg, (void*)&cur,
                    (void*)&bsum,   (void*)&csr,    (void*)&Ee,  (void*)&nn,  (void*)&x,
                    (void*)&x16,    (void*)&W0,     (void*)&Wt0, (void*)&W1,  (void*)&Wt1,
                    (void*)&W2,     (void*)&Wt2};
    hipLaunchCooperativeKernel((const void*)k_build, dim3(1024), dim3(256), args, 0, stream);
  }

  dim3 gg(ceil_div(kN, 128), 2);
  dim3 gg2(ceil_div(kN, 128), 1);
  int wpn_blocks = ceil_div(kN, 4);  // wave-per-node kernels

  // Layer 0
  k_mfma_gemm<<<gg, 256, 0, stream>>>(x16, Wt0, h16, as0, ad0, a_s, a_d, kN, 256, 256, 256, 4,
                                      256);
  k_attn_agg256<<<wpn_blocks, 256, 0, stream>>>(rp, csr, (const _Float16*)h16, a_s, a_d, b0, bg0,
                                                bb0, bm0, bv0, act16, kN);

  // Layer 1
  k_mfma_gemm<<<gg, 256, 0, stream>>>(act16, Wt1, h16, as1, ad1, a_s, a_d, kN, 256, 256, 256, 4,
                                      256);
  k_attn_agg256<<<wpn_blocks, 256, 0, stream>>>(rp, csr, (const _Float16*)h16, a_s, a_d, b1, bg1,
                                                bb1, bm1, bv1, act16, kN);

  // Layer 2: h2 [N,40] packed (row stride 40) in h16
  k_mfma_gemm<<<gg2, 256, 0, stream>>>(act16, Wt2, h16, as2, ad2, a_s, a_d, kN, 256, 40, 40, 1,
                                       40);
  k_attn_agg40<<<wpn_blocks, 256, 0, stream>>>(rp, csr, (const _Float16*)h16, a_s, a_d, b2, out,
                                               kN);
}

// Round 7
// 474.236 us; speedup vs baseline: 2.0950x; 2.0950x over previous
//
#include <hip/hip_runtime.h>
#include <cstdint>
#include <cstddef>

constexpr int kN = 50000;
constexpr float kSlope = 0.2f;
constexpr float kBnEps = 1e-5f;

static inline int ceil_div(int a, int b) { return (a + b - 1) / b; }

typedef __attribute__((ext_vector_type(8))) _Float16 half8;
typedef __attribute__((ext_vector_type(8))) unsigned short ushortx8;
typedef __attribute__((ext_vector_type(4))) float f32x4;

__device__ inline unsigned short f2h_us(float f) {
  _Float16 h = (_Float16)f;
  return *(unsigned short*)&h;
}

// async global->LDS, 16B per lane, dest = wave-uniform base + lane*16
__device__ inline void gload16(const void* g, void* l) {
  __builtin_amdgcn_global_load_lds((const __attribute__((address_space(1))) unsigned int*)g,
                                   (__attribute__((address_space(3))) unsigned int*)l, 16, 0, 0);
}

// ---------------- CSR build (separate kernels; grid.sync measured ~107us/sync on gfx950,
// so cooperative fusion is strictly worse than relaunching) ----------------

__global__ void k_degree(const int* __restrict__ dst, int* __restrict__ deg, int E) {
  int e = blockIdx.x * blockDim.x + threadIdx.x;
  if (e < E) atomicAdd(&deg[dst[e]], 1);
}

__global__ void k_scan1(const int* __restrict__ deg, int* __restrict__ rp,
                        int* __restrict__ bsum, int n) {
  __shared__ int sm[256];
  int i = blockIdx.x * 256 + threadIdx.x;
  int v = (i < n) ? deg[i] : 0;
  sm[threadIdx.x] = v;
  __syncthreads();
  for (int off = 1; off < 256; off <<= 1) {
    int t = (threadIdx.x >= off) ? sm[threadIdx.x - off] : 0;
    __syncthreads();
    sm[threadIdx.x] += t;
    __syncthreads();
  }
  if (i < n) rp[i + 1] = sm[threadIdx.x];
  if (threadIdx.x == 255) bsum[blockIdx.x] = sm[255];
}

__global__ void k_scan2(int* bsum, int nb) {
  __shared__ int sm[256];
  int v = (threadIdx.x < nb) ? bsum[threadIdx.x] : 0;
  sm[threadIdx.x] = v;
  __syncthreads();
  for (int off = 1; off < 256; off <<= 1) {
    int t = (threadIdx.x >= off) ? sm[threadIdx.x - off] : 0;
    __syncthreads();
    sm[threadIdx.x] += t;
    __syncthreads();
  }
  if (threadIdx.x < nb) bsum[threadIdx.x] = sm[threadIdx.x] - v;  // exclusive
}

__global__ void k_scan3(int* __restrict__ rp, const int* __restrict__ bsum, int n) {
  int i = blockIdx.x * 256 + threadIdx.x;
  if (i < n) rp[i + 1] += bsum[blockIdx.x];
  if (i == 0) rp[0] = 0;
}

__global__ void k_scatter(const int* __restrict__ src, const int* __restrict__ dst,
                          const int* __restrict__ rp, int* __restrict__ cur,
                          int* __restrict__ csr, int E) {
  int e = blockIdx.x * blockDim.x + threadIdx.x;
  if (e < E) {
    int d = dst[e];
    int pos = rp[d] + atomicAdd(&cur[d], 1);
    csr[pos] = src[e];
  }
}

// ---------------- prep: fused fp32->f16 cast + all weight transposes ----------------

__global__ void k_prep(const float* __restrict__ x, unsigned short* __restrict__ x16,
                       const float* __restrict__ W0, unsigned short* __restrict__ Wt0,
                       const float* __restrict__ W1, unsigned short* __restrict__ Wt1,
                       const float* __restrict__ W2, unsigned short* __restrict__ Wt2) {
  int i = blockIdx.x * blockDim.x + threadIdx.x;
  const int N4 = kN * 64;  // float4 units of x
  const int S0 = 256 * 256, S1 = 256 * 256, S2 = 128 * 256;
  if (i < N4) {
    float4 v = ((const float4*)x)[i];
    ushort4 o;
    o.x = f2h_us(v.x);
    o.y = f2h_us(v.y);
    o.z = f2h_us(v.z);
    o.w = f2h_us(v.w);
    ((ushort4*)x16)[i] = o;
  } else {
    int j = i - N4;
    if (j < S0) {
      int nc = j >> 8, k = j & 255;
      Wt0[j] = f2h_us(W0[(size_t)k * 256 + nc]);
    } else if (j < S0 + S1) {
      int t = j - S0;
      int nc = t >> 8, k = t & 255;
      Wt1[t] = f2h_us(W1[(size_t)k * 256 + nc]);
    } else if (j < S0 + S1 + S2) {
      int t = j - S0 - S1;
      int nc = t >> 8, k = t & 255;
      Wt2[t] = (nc < 40) ? f2h_us(W2[(size_t)k * 40 + nc]) : (unsigned short)0;
    }
  }
}

// ---------------- f16 MFMA GEMM, global_load_lds staging, fused attn projection ----------
// Single-buffered (R2 structure); dbuf variant was within noise, keep the simpler one.

__global__ __launch_bounds__(256) void k_mfma_gemm(
    const unsigned short* __restrict__ A, const unsigned short* __restrict__ Bt,
    unsigned short* __restrict__ C, const float* __restrict__ asrc,
    const float* __restrict__ adst, float* __restrict__ a_s, float* __restrict__ a_d, int M,
    int K, int Nc, int ldc, int heads, int acols) {
  constexpr int BM = 128, BK = 32;
  // linear [BM][BK] halves: fragment read (wm+i*16+l16)*BK + quad*8 covers a contiguous
  // 1KB region per wave -> zero bank conflicts (measured), matches gload_lds landing.
  __shared__ unsigned short As[BM * BK];
  __shared__ unsigned short Bs[BM * BK];
  int tid = threadIdx.x;
  int wave = tid >> 6, lane = tid & 63;
  int quad = lane >> 4, l16 = lane & 15;
  int wm = (wave & 1) * 64, wn = (wave >> 1) * 64;
  int bm = blockIdx.x * BM, bn = blockIdx.y * BM;
  // staging coords: chunk = 16 rows x 64B = 1KB per instruction
  int srow = lane >> 2;   // 0..15 row within chunk
  int spart = lane & 3;   // 16B part within 64B row
  f32x4 acc[4][4] = {};
  for (int k0 = 0; k0 < K; k0 += BK) {
#pragma unroll
    for (int it = 0; it < 2; it++) {
      int chunk = wave * 2 + it;          // 0..7
      int row = chunk * 16 + srow;        // 0..127
      // NOTE: no M-guard on A reads: last block's stray rows land in adjacent
      // workspace buffers (x16/act16 are followed by other allocations); all
      // result writes are guarded by row < M.
      gload16(A + (size_t)(bm + row) * K + k0 + spart * 8, As + chunk * 512);
      gload16(Bt + (size_t)(bn + row) * K + k0 + spart * 8, Bs + chunk * 512);
    }
    __syncthreads();
    half8 af[4], bf[4];
#pragma unroll
    for (int i = 0; i < 4; i++) {
      af[i] = *(const half8*)(As + (wm + i * 16 + l16) * BK + quad * 8);
      bf[i] = *(const half8*)(Bs + (wn + i * 16 + l16) * BK + quad * 8);
    }
#pragma unroll
    for (int i = 0; i < 4; i++)
#pragma unroll
      for (int j = 0; j < 4; j++)
        acc[i][j] = __builtin_amdgcn_mfma_f32_16x16x32_f16(af[i], bf[j], acc[i][j], 0, 0, 0);
    __syncthreads();
  }
  // C write (f16)
#pragma unroll
  for (int i = 0; i < 4; i++) {
#pragma unroll
    for (int j = 0; j < 4; j++) {
      int col = bn + wn + j * 16 + l16;
      if (col >= Nc) continue;
#pragma unroll
      for (int r = 0; r < 4; r++) {
        int row = bm + wm + i * 16 + quad * 4 + r;
        if (row < M) C[(size_t)row * ldc + col] = f2h_us(acc[i][j][r]);
      }
    }
  }
  // fused attention projection epilogue
  int ghead = (bn + wn) >> 6;
  if (ghead < heads) {
    float asv[4], adv[4];
#pragma unroll
    for (int j = 0; j < 4; j++) {
      int col = bn + wn + j * 16 + l16;
      bool ok = col < acols;
      asv[j] = ok ? asrc[col] : 0.f;
      adv[j] = ok ? adst[col] : 0.f;
    }
#pragma unroll
    for (int i = 0; i < 4; i++) {
#pragma unroll
      for (int r = 0; r < 4; r++) {
        float s = acc[i][0][r] * asv[0] + acc[i][1][r] * asv[1] + acc[i][2][r] * asv[2] +
                  acc[i][3][r] * asv[3];
        float d = acc[i][0][r] * adv[0] + acc[i][1][r] * adv[1] + acc[i][2][r] * adv[2] +
                  acc[i][3][r] * adv[3];
#pragma unroll
        for (int mask = 1; mask <= 8; mask <<= 1) {
          s += __shfl_xor(s, mask, 64);
          d += __shfl_xor(d, mask, 64);
        }
        if (l16 == 0) {
          int row = bm + wm + i * 16 + quad * 4 + r;
          if (row < M) {
            a_s[row * heads + ghead] = s;
            a_d[row * heads + ghead] = d;
          }
        }
      }
    }
  }
}

// ---------------- fused softmax+aggregation: wave per node, 256 ch, f16 h ----------------
// R0 structure — FROZEN (locally optimal; survived R1/R2/R5 restructurings).
// R7: node-range [n0,n1) parameter so each layer runs as TWO half dispatches —
// identical work/numerics, ~35us each, vacating rocprof top-5 to expose the
// (so far invisible) GEMM/agg40 durations.

__global__ __launch_bounds__(256) void k_attn_agg256(
    const int* __restrict__ rp, const int* __restrict__ csr, const _Float16* __restrict__ h,
    const float* __restrict__ a_s, const float* __restrict__ a_d, const float* __restrict__ bias,
    const float* __restrict__ bg, const float* __restrict__ bb, const float* __restrict__ bm,
    const float* __restrict__ bv, unsigned short* __restrict__ out, int n0, int n1) {
  int wid = (blockIdx.x * blockDim.x + threadIdx.x) >> 6;
  int lane = threadIdx.x & 63;
  int n = n0 + wid;
  if (n >= n1) return;
  int beg = rp[n], end = rp[n + 1];
  int half = lane >> 5, l32 = lane & 31;
  int head = l32 >> 3;  // 8 lanes x 8 ch per head
  int c = l32 * 8;
  float ad = a_d[n * 4 + head];
  float acc[8] = {};
  float psum = 0.f;
  int e = beg;
  for (; e + 8 <= end; e += 8) {
    int s0 = csr[e + half];
    int s1 = csr[e + 2 + half];
    int s2 = csr[e + 4 + half];
    int s3 = csr[e + 6 + half];
    float x0 = a_s[s0 * 4 + head] + ad;
    float x1 = a_s[s1 * 4 + head] + ad;
    float x2 = a_s[s2 * 4 + head] + ad;
    float x3 = a_s[s3 * 4 + head] + ad;
    half8 v0 = *(const half8*)(h + (size_t)s0 * 256 + c);
    half8 v1 = *(const half8*)(h + (size_t)s1 * 256 + c);
    half8 v2 = *(const half8*)(h + (size_t)s2 * 256 + c);
    half8 v3 = *(const half8*)(h + (size_t)s3 * 256 + c);
    x0 = x0 > 0.f ? x0 : x0 * kSlope;
    x1 = x1 > 0.f ? x1 : x1 * kSlope;
    x2 = x2 > 0.f ? x2 : x2 * kSlope;
    x3 = x3 > 0.f ? x3 : x3 * kSlope;
    float p0 = __expf(x0), p1 = __expf(x1);
    float p2 = __expf(x2), p3 = __expf(x3);
    psum += (p0 + p1) + (p2 + p3);
#pragma unroll
    for (int j = 0; j < 8; j++) {
      acc[j] += (float)v0[j] * p0 + (float)v1[j] * p1;
      acc[j] += (float)v2[j] * p2 + (float)v3[j] * p3;
    }
  }
  for (; e + 2 <= end; e += 2) {
    int s0 = csr[e + half];
    float x0 = a_s[s0 * 4 + head] + ad;
    x0 = x0 > 0.f ? x0 : x0 * kSlope;
    float p0 = __expf(x0);
    psum += p0;
    half8 v0 = *(const half8*)(h + (size_t)s0 * 256 + c);
#pragma unroll
    for (int j = 0; j < 8; j++) acc[j] += (float)v0[j] * p0;
  }
  if (e < end && half == 0) {
    int s0 = csr[e];
    float x0 = a_s[s0 * 4 + head] + ad;
    x0 = x0 > 0.f ? x0 : x0 * kSlope;
    float p0 = __expf(x0);
    psum += p0;
    half8 v0 = *(const half8*)(h + (size_t)s0 * 256 + c);
#pragma unroll
    for (int j = 0; j < 8; j++) acc[j] += (float)v0[j] * p0;
  }
  psum += __shfl_xor(psum, 32, 64);
#pragma unroll
  for (int j = 0; j < 8; j++) acc[j] += __shfl_xor(acc[j], 32, 64);
  if (half == 0) {
    float rden = 1.f / (psum + 1e-16f);
    ushortx8 o;
#pragma unroll
    for (int j = 0; j < 8; j++) {
      float v = acc[j] * rden + bias[c + j];
      v = bg[c + j] * (v - bm[c + j]) * rsqrtf(bv[c + j] + kBnEps) + bb[c + j];
      v = v > 0.f ? v : (__expf(v) - 1.f);  // ELU
      o[j] = f2h_us(v);
    }
    *(ushortx8*)(out + (size_t)n * 256 + c) = o;
  }
}

// ---------------- fused softmax+aggregation: wave per node, 40 ch (packed, stride 40) ----

__global__ __launch_bounds__(256) void k_attn_agg40(
    const int* __restrict__ rp, const int* __restrict__ csr, const _Float16* __restrict__ h,
    const float* __restrict__ a_s, const float* __restrict__ a_d, const float* __restrict__ bias,
    float* __restrict__ out, int n_nodes) {
  int wid = (blockIdx.x * blockDim.x + threadIdx.x) >> 6;
  int lane = threadIdx.x & 63;
  if (wid >= n_nodes) return;
  int n = wid;
  int beg = rp[n], end = rp[n + 1];
  float ad = a_d[n];
  int grp = lane >> 3, l8 = lane & 7;
  int c = l8 * 8;  // valid channels only for l8 < 5
  bool act = l8 < 5;
  float acc[8] = {};
  float psum = 0.f;
  for (int base = beg; base < end; base += 16) {
    int e0 = base + grp;
    int e1 = base + 8 + grp;
    if (e0 < end) {
      int s = csr[e0];
      float x = a_s[s] + ad;
      x = x > 0.f ? x : x * kSlope;
      float p = __expf(x);
      psum += p;
      if (act) {
        half8 hv = *(const half8*)(h + (size_t)s * 40 + c);
#pragma unroll
        for (int j = 0; j < 8; j++) acc[j] += (float)hv[j] * p;
      }
    }
    if (e1 < end) {
      int s = csr[e1];
      float x = a_s[s] + ad;
      x = x > 0.f ? x : x * kSlope;
      float p = __expf(x);
      psum += p;
      if (act) {
        half8 hv = *(const half8*)(h + (size_t)s * 40 + c);
#pragma unroll
        for (int j = 0; j < 8; j++) acc[j] += (float)hv[j] * p;
      }
    }
  }
#pragma unroll
  for (int mask = 8; mask <= 32; mask <<= 1) psum += __shfl_xor(psum, mask, 64);
#pragma unroll
  for (int j = 0; j < 8; j++) {
#pragma unroll
    for (int mask = 8; mask <= 32; mask <<= 1) acc[j] += __shfl_xor(acc[j], mask, 64);
  }
  if (lane < 5) {  // channels 0..39
    float rden = 1.f / (psum + 1e-16f);
    float4 o0, o1;
    o0.x = acc[0] * rden + bias[c + 0];
    o0.y = acc[1] * rden + bias[c + 1];
    o0.z = acc[2] * rden + bias[c + 2];
    o0.w = acc[3] * rden + bias[c + 3];
    o1.x = acc[4] * rden + bias[c + 4];
    o1.y = acc[5] * rden + bias[c + 5];
    o1.z = acc[6] * rden + bias[c + 6];
    o1.w = acc[7] * rden + bias[c + 7];
    *(float4*)(out + (size_t)n * 40 + c) = o0;
    *(float4*)(out + (size_t)n * 40 + c + 4) = o1;
  }
}

// ---------------- driver ----------------

extern "C" void kernel_launch(void* const* d_in, const int* in_sizes, int n_in, void* d_out,
                              int out_size, void* d_ws, size_t ws_size, hipStream_t stream) {
  const float* x = (const float*)d_in[0];
  const int* ei = (const int*)d_in[1];
  const float* W0 = (const float*)d_in[2];
  const float* as0 = (const float*)d_in[3];
  const float* ad0 = (const float*)d_in[4];
  const float* b0 = (const float*)d_in[5];
  const float* bg0 = (const float*)d_in[6];
  const float* bb0 = (const float*)d_in[7];
  const float* bm0 = (const float*)d_in[8];
  const float* bv0 = (const float*)d_in[9];
  const float* W1 = (const float*)d_in[10];
  const float* as1 = (const float*)d_in[11];
  const float* ad1 = (const float*)d_in[12];
  const float* b1 = (const float*)d_in[13];
  const float* bg1 = (const float*)d_in[14];
  const float* bb1 = (const float*)d_in[15];
  const float* bm1 = (const float*)d_in[16];
  const float* bv1 = (const float*)d_in[17];
  const float* W2 = (const float*)d_in[18];
  const float* as2 = (const float*)d_in[19];
  const float* ad2 = (const float*)d_in[20];
  const float* b2 = (const float*)d_in[21];
  float* out = (float*)d_out;

  const int E = in_sizes[1] / 2;
  const int* srcIdx = ei;
  const int* dstIdx = ei + E;

  char* p = (char*)d_ws;
  auto alloc = [&](size_t bytes) -> void* {
    void* r = (void*)p;
    p += (bytes + 255) & ~(size_t)255;
    return r;
  };
  int* rp = (int*)alloc((kN + 1) * sizeof(int));
  int* degcur = (int*)alloc((size_t)2 * kN * sizeof(int));  // deg | cursor
  int* deg = degcur;
  int* cur = degcur + kN;
  int* bsum = (int*)alloc(256 * sizeof(int));
  int* csr = (int*)alloc((size_t)E * sizeof(int));
  float* a_s = (float*)alloc((size_t)kN * 4 * sizeof(float));
  float* a_d = (float*)alloc((size_t)kN * 4 * sizeof(float));
  unsigned short* x16 = (unsigned short*)alloc((size_t)kN * 256 * 2);
  unsigned short* h16 = (unsigned short*)alloc((size_t)kN * 256 * 2);
  unsigned short* act16 = (unsigned short*)alloc((size_t)kN * 256 * 2);
  unsigned short* Wt0 = (unsigned short*)alloc((size_t)256 * 256 * 2);
  unsigned short* Wt1 = (unsigned short*)alloc((size_t)256 * 256 * 2);
  unsigned short* Wt2 = (unsigned short*)alloc((size_t)128 * 256 * 2);

  const int eb = ceil_div(E, 256);
  const int nb = ceil_div(kN, 256);

  // CSR build (edge_index identical for all layers)
  hipMemsetAsync(degcur, 0, (size_t)2 * kN * sizeof(int), stream);
  k_degree<<<eb, 256, 0, stream>>>(dstIdx, deg, E);
  k_scan1<<<nb, 256, 0, stream>>>(deg, rp, bsum, kN);
  k_scan2<<<1, 256, 0, stream>>>(bsum, nb);
  k_scan3<<<nb, 256, 0, stream>>>(rp, bsum, kN);
  k_scatter<<<eb, 256, 0, stream>>>(srcIdx, dstIdx, rp, cur, csr, E);

  // prep: fused cast + weight transposes (one launch)
  const int prep_items = kN * 64 + 256 * 256 * 2 + 128 * 256;
  k_prep<<<ceil_div(prep_items, 256), 256, 0, stream>>>(x, x16, W0, Wt0, W1, Wt1, W2, Wt2);

  dim3 gg(ceil_div(kN, 128), 2);
  dim3 gg2(ceil_div(kN, 128), 1);
  const int nhalf = kN / 2;                      // 25000
  int hblocks = ceil_div(nhalf, 4);              // blocks per half
  int wpn_blocks = ceil_div(kN, 4);              // wave-per-node (agg40)

  // Layer 0
  k_mfma_gemm<<<gg, 256, 0, stream>>>(x16, Wt0, h16, as0, ad0, a_s, a_d, kN, 256, 256, 256, 4,
                                      256);
  k_attn_agg256<<<hblocks, 256, 0, stream>>>(rp, csr, (const _Float16*)h16, a_s, a_d, b0, bg0,
                                             bb0, bm0, bv0, act16, 0, nhalf);
  k_attn_agg256<<<hblocks, 256, 0, stream>>>(rp, csr, (const _Float16*)h16, a_s, a_d, b0, bg0,
                                             bb0, bm0, bv0, act16, nhalf, kN);

  // Layer 1
  k_mfma_gemm<<<gg, 256, 0, stream>>>(act16, Wt1, h16, as1, ad1, a_s, a_d, kN, 256, 256, 256, 4,
                                      256);
  k_attn_agg256<<<hblocks, 256, 0, stream>>>(rp, csr, (const _Float16*)h16, a_s, a_d, b1, bg1,
                                             bb1, bm1, bv1, act16, 0, nhalf);
  k_attn_agg256<<<hblocks, 256, 0, stream>>>(rp, csr, (const _Float16*)h16, a_s, a_d, b1, bg1,
                                             bb1, bm1, bv1, act16, nhalf, kN);

  // Layer 2: h2 [N,40] packed (row stride 40) in h16
  k_mfma_gemm<<<gg2, 256, 0, stream>>>(act16, Wt2, h16, as2, ad2, a_s, a_d, kN, 256, 40, 40, 1,
                                       40);
  k_attn_agg40<<<wpn_blocks, 256, 0, stream>>>(rp, csr, (const _Float16*)h16, a_s, a_d, b2, out,
                                               kN);
}

// Round 8
// 445.770 us; speedup vs baseline: 2.2288x; 1.0639x over previous
//
#include <hip/hip_runtime.h>
#include <cstdint>
#include <cstddef>

constexpr int kN = 50000;
constexpr float kSlope = 0.2f;
constexpr float kBnEps = 1e-5f;

static inline int ceil_div(int a, int b) { return (a + b - 1) / b; }

typedef __attribute__((ext_vector_type(8))) _Float16 half8;
typedef __attribute__((ext_vector_type(8))) unsigned short ushortx8;
typedef __attribute__((ext_vector_type(4))) float f32x4;

__device__ inline unsigned short f2h_us(float f) {
  _Float16 h = (_Float16)f;
  return *(unsigned short*)&h;
}

// async global->LDS, 16B per lane, dest = wave-uniform base + lane*16
__device__ inline void gload16(const void* g, void* l) {
  __builtin_amdgcn_global_load_lds((const __attribute__((address_space(1))) unsigned int*)g,
                                   (__attribute__((address_space(3))) unsigned int*)l, 16, 0, 0);
}

// ---------------- merged: degree histogram + prep (independent work, one dispatch) -------
// Degree atomics are fire-and-forget (no return) -> prep streaming starts while they
// are in flight. 2048 blocks = full co-residency.

__global__ void k_prep_degree(const int* __restrict__ dst, int* __restrict__ deg, int E,
                              const float* __restrict__ x, unsigned short* __restrict__ x16,
                              const float* __restrict__ W0, unsigned short* __restrict__ Wt0,
                              const float* __restrict__ W1, unsigned short* __restrict__ Wt1,
                              const float* __restrict__ W2, unsigned short* __restrict__ Wt2) {
  const int tid = blockIdx.x * blockDim.x + threadIdx.x;
  const int nthr = gridDim.x * blockDim.x;
  for (int e = tid; e < E; e += nthr) atomicAdd(&deg[dst[e]], 1);
  const int N4 = kN * 64;  // float4 units of x
  const int S0 = 256 * 256, S1 = 256 * 256, S2 = 128 * 256;
  const int total = N4 + S0 + S1 + S2;
  for (int i = tid; i < total; i += nthr) {
    if (i < N4) {
      float4 v = ((const float4*)x)[i];
      ushort4 o;
      o.x = f2h_us(v.x);
      o.y = f2h_us(v.y);
      o.z = f2h_us(v.z);
      o.w = f2h_us(v.w);
      ((ushort4*)x16)[i] = o;
    } else {
      int j = i - N4;
      if (j < S0) {
        int nc = j >> 8, k = j & 255;
        Wt0[j] = f2h_us(W0[(size_t)k * 256 + nc]);
      } else if (j < S0 + S1) {
        int t = j - S0;
        int nc = t >> 8, k = t & 255;
        Wt1[t] = f2h_us(W1[(size_t)k * 256 + nc]);
      } else {
        int t = j - S0 - S1;
        int nc = t >> 8, k = t & 255;
        Wt2[t] = (nc < 40) ? f2h_us(W2[(size_t)k * 40 + nc]) : (unsigned short)0;
      }
    }
  }
}

// ---------------- scans ----------------

__global__ void k_scan1(const int* __restrict__ deg, int* __restrict__ rp,
                        int* __restrict__ bsum, int n) {
  __shared__ int sm[256];
  int i = blockIdx.x * 256 + threadIdx.x;
  int v = (i < n) ? deg[i] : 0;
  sm[threadIdx.x] = v;
  __syncthreads();
  for (int off = 1; off < 256; off <<= 1) {
    int t = (threadIdx.x >= off) ? sm[threadIdx.x - off] : 0;
    __syncthreads();
    sm[threadIdx.x] += t;
    __syncthreads();
  }
  if (i < n) rp[i + 1] = sm[threadIdx.x];
  if (threadIdx.x == 255) bsum[blockIdx.x] = sm[255];
}

__global__ void k_scan2(int* bsum, int nb) {
  __shared__ int sm[256];
  int v = (threadIdx.x < nb) ? bsum[threadIdx.x] : 0;
  sm[threadIdx.x] = v;
  __syncthreads();
  for (int off = 1; off < 256; off <<= 1) {
    int t = (threadIdx.x >= off) ? sm[threadIdx.x - off] : 0;
    __syncthreads();
    sm[threadIdx.x] += t;
    __syncthreads();
  }
  if (threadIdx.x < nb) bsum[threadIdx.x] = sm[threadIdx.x] - v;  // exclusive
}

__global__ void k_scan3(int* __restrict__ rp, const int* __restrict__ bsum, int n) {
  int i = blockIdx.x * 256 + threadIdx.x;
  if (i < n) rp[i + 1] += bsum[blockIdx.x];
  if (i == 0) rp[0] = 0;
}

// ---------------- GEMM body (device fn): f16 MFMA, gload_lds staging, attn epilogue ------

__device__ __forceinline__ void gemm_body(
    int bx, int by, const unsigned short* __restrict__ A, const unsigned short* __restrict__ Bt,
    unsigned short* __restrict__ C, const float* __restrict__ asrc,
    const float* __restrict__ adst, float* __restrict__ a_s, float* __restrict__ a_d, int M,
    int K, int Nc, int ldc, int heads, int acols) {
  constexpr int BM = 128, BK = 32;
  __shared__ unsigned short As[BM * BK];
  __shared__ unsigned short Bs[BM * BK];
  int tid = threadIdx.x;
  int wave = tid >> 6, lane = tid & 63;
  int quad = lane >> 4, l16 = lane & 15;
  int wm = (wave & 1) * 64, wn = (wave >> 1) * 64;
  int bm = bx * BM, bn = by * BM;
  int srow = lane >> 2;  // 0..15 row within 16-row chunk
  int spart = lane & 3;  // 16B part within 64B row
  f32x4 acc[4][4] = {};
  for (int k0 = 0; k0 < K; k0 += BK) {
#pragma unroll
    for (int it = 0; it < 2; it++) {
      int chunk = wave * 2 + it;    // 0..7
      int row = chunk * 16 + srow;  // 0..127
      // no M-guard on A reads: stray rows land in adjacent workspace buffers;
      // all result writes are guarded by row < M.
      gload16(A + (size_t)(bm + row) * K + k0 + spart * 8, As + chunk * 512);
      gload16(Bt + (size_t)(bn + row) * K + k0 + spart * 8, Bs + chunk * 512);
    }
    __syncthreads();
    half8 af[4], bf[4];
#pragma unroll
    for (int i = 0; i < 4; i++) {
      af[i] = *(const half8*)(As + (wm + i * 16 + l16) * BK + quad * 8);
      bf[i] = *(const half8*)(Bs + (wn + i * 16 + l16) * BK + quad * 8);
    }
#pragma unroll
    for (int i = 0; i < 4; i++)
#pragma unroll
      for (int j = 0; j < 4; j++)
        acc[i][j] = __builtin_amdgcn_mfma_f32_16x16x32_f16(af[i], bf[j], acc[i][j], 0, 0, 0);
    __syncthreads();
  }
#pragma unroll
  for (int i = 0; i < 4; i++) {
#pragma unroll
    for (int j = 0; j < 4; j++) {
      int col = bn + wn + j * 16 + l16;
      if (col >= Nc) continue;
#pragma unroll
      for (int r = 0; r < 4; r++) {
        int row = bm + wm + i * 16 + quad * 4 + r;
        if (row < M) C[(size_t)row * ldc + col] = f2h_us(acc[i][j][r]);
      }
    }
  }
  int ghead = (bn + wn) >> 6;
  if (ghead < heads) {
    float asv[4], adv[4];
#pragma unroll
    for (int j = 0; j < 4; j++) {
      int col = bn + wn + j * 16 + l16;
      bool ok = col < acols;
      asv[j] = ok ? asrc[col] : 0.f;
      adv[j] = ok ? adst[col] : 0.f;
    }
#pragma unroll
    for (int i = 0; i < 4; i++) {
#pragma unroll
      for (int r = 0; r < 4; r++) {
        float s = acc[i][0][r] * asv[0] + acc[i][1][r] * asv[1] + acc[i][2][r] * asv[2] +
                  acc[i][3][r] * asv[3];
        float d = acc[i][0][r] * adv[0] + acc[i][1][r] * adv[1] + acc[i][2][r] * adv[2] +
                  acc[i][3][r] * adv[3];
#pragma unroll
        for (int mask = 1; mask <= 8; mask <<= 1) {
          s += __shfl_xor(s, mask, 64);
          d += __shfl_xor(d, mask, 64);
        }
        if (l16 == 0) {
          int row = bm + wm + i * 16 + quad * 4 + r;
          if (row < M) {
            a_s[row * heads + ghead] = s;
            a_d[row * heads + ghead] = d;
          }
        }
      }
    }
  }
}

__global__ __launch_bounds__(256) void k_mfma_gemm(
    const unsigned short* __restrict__ A, const unsigned short* __restrict__ Bt,
    unsigned short* __restrict__ C, const float* __restrict__ asrc,
    const float* __restrict__ adst, float* __restrict__ a_s, float* __restrict__ a_d, int M,
    int K, int Nc, int ldc, int heads, int acols) {
  gemm_body(blockIdx.x, blockIdx.y, A, Bt, C, asrc, adst, a_s, a_d, M, K, Nc, ldc, heads, acols);
}

// ---------------- merged: GEMM layer-0 + CSR scatter (independent, one dispatch) ---------
// GEMM blocks first (VGPR-heavy, ~3/CU) — scatter blocks fill residual CU capacity,
// hiding scatter's 44us random-write latency under the GEMM.

__global__ __launch_bounds__(256) void k_gemm0_scatter(
    const unsigned short* __restrict__ A, const unsigned short* __restrict__ Bt,
    unsigned short* __restrict__ C, const float* __restrict__ asrc,
    const float* __restrict__ adst, float* __restrict__ a_s, float* __restrict__ a_d, int M,
    int K, int gemmBlocks, const int* __restrict__ src, const int* __restrict__ dst,
    const int* __restrict__ rp, int* __restrict__ cur, int* __restrict__ csr, int E) {
  if ((int)blockIdx.x < gemmBlocks) {
    int bx = blockIdx.x >> 1, by = blockIdx.x & 1;
    gemm_body(bx, by, A, Bt, C, asrc, adst, a_s, a_d, M, K, 256, 256, 4, 256);
  } else {
    int e = (blockIdx.x - gemmBlocks) * 256 + threadIdx.x;
    if (e < E) {
      int d = dst[e];
      int pos = rp[d] + atomicAdd(&cur[d], 1);
      csr[pos] = src[e];
    }
  }
}

// ---------------- fused softmax+aggregation: wave per node, 256 ch, f16 h ----------------
// R0 structure — FROZEN (locally optimal; survived R1/R2/R5 restructurings).

__global__ __launch_bounds__(256) void k_attn_agg256(
    const int* __restrict__ rp, const int* __restrict__ csr, const _Float16* __restrict__ h,
    const float* __restrict__ a_s, const float* __restrict__ a_d, const float* __restrict__ bias,
    const float* __restrict__ bg, const float* __restrict__ bb, const float* __restrict__ bm,
    const float* __restrict__ bv, unsigned short* __restrict__ out, int n_nodes) {
  int wid = (blockIdx.x * blockDim.x + threadIdx.x) >> 6;
  int lane = threadIdx.x & 63;
  if (wid >= n_nodes) return;
  int n = wid;
  int beg = rp[n], end = rp[n + 1];
  int half = lane >> 5, l32 = lane & 31;
  int head = l32 >> 3;  // 8 lanes x 8 ch per head
  int c = l32 * 8;
  float ad = a_d[n * 4 + head];
  float acc[8] = {};
  float psum = 0.f;
  int e = beg;
  for (; e + 8 <= end; e += 8) {
    int s0 = csr[e + half];
    int s1 = csr[e + 2 + half];
    int s2 = csr[e + 4 + half];
    int s3 = csr[e + 6 + half];
    float x0 = a_s[s0 * 4 + head] + ad;
    float x1 = a_s[s1 * 4 + head] + ad;
    float x2 = a_s[s2 * 4 + head] + ad;
    float x3 = a_s[s3 * 4 + head] + ad;
    half8 v0 = *(const half8*)(h + (size_t)s0 * 256 + c);
    half8 v1 = *(const half8*)(h + (size_t)s1 * 256 + c);
    half8 v2 = *(const half8*)(h + (size_t)s2 * 256 + c);
    half8 v3 = *(const half8*)(h + (size_t)s3 * 256 + c);
    x0 = x0 > 0.f ? x0 : x0 * kSlope;
    x1 = x1 > 0.f ? x1 : x1 * kSlope;
    x2 = x2 > 0.f ? x2 : x2 * kSlope;
    x3 = x3 > 0.f ? x3 : x3 * kSlope;
    float p0 = __expf(x0), p1 = __expf(x1);
    float p2 = __expf(x2), p3 = __expf(x3);
    psum += (p0 + p1) + (p2 + p3);
#pragma unroll
    for (int j = 0; j < 8; j++) {
      acc[j] += (float)v0[j] * p0 + (float)v1[j] * p1;
      acc[j] += (float)v2[j] * p2 + (float)v3[j] * p3;
    }
  }
  for (; e + 2 <= end; e += 2) {
    int s0 = csr[e + half];
    float x0 = a_s[s0 * 4 + head] + ad;
    x0 = x0 > 0.f ? x0 : x0 * kSlope;
    float p0 = __expf(x0);
    psum += p0;
    half8 v0 = *(const half8*)(h + (size_t)s0 * 256 + c);
#pragma unroll
    for (int j = 0; j < 8; j++) acc[j] += (float)v0[j] * p0;
  }
  if (e < end && half == 0) {
    int s0 = csr[e];
    float x0 = a_s[s0 * 4 + head] + ad;
    x0 = x0 > 0.f ? x0 : x0 * kSlope;
    float p0 = __expf(x0);
    psum += p0;
    half8 v0 = *(const half8*)(h + (size_t)s0 * 256 + c);
#pragma unroll
    for (int j = 0; j < 8; j++) acc[j] += (float)v0[j] * p0;
  }
  psum += __shfl_xor(psum, 32, 64);
#pragma unroll
  for (int j = 0; j < 8; j++) acc[j] += __shfl_xor(acc[j], 32, 64);
  if (half == 0) {
    float rden = 1.f / (psum + 1e-16f);
    ushortx8 o;
#pragma unroll
    for (int j = 0; j < 8; j++) {
      float v = acc[j] * rden + bias[c + j];
      v = bg[c + j] * (v - bm[c + j]) * rsqrtf(bv[c + j] + kBnEps) + bb[c + j];
      v = v > 0.f ? v : (__expf(v) - 1.f);  // ELU
      o[j] = f2h_us(v);
    }
    *(ushortx8*)(out + (size_t)n * 256 + c) = o;
  }
}

// ---------------- fused softmax+aggregation: wave per node, 40 ch (packed, stride 40) ----

__global__ __launch_bounds__(256) void k_attn_agg40(
    const int* __restrict__ rp, const int* __restrict__ csr, const _Float16* __restrict__ h,
    const float* __restrict__ a_s, const float* __restrict__ a_d, const float* __restrict__ bias,
    float* __restrict__ out, int n_nodes) {
  int wid = (blockIdx.x * blockDim.x + threadIdx.x) >> 6;
  int lane = threadIdx.x & 63;
  if (wid >= n_nodes) return;
  int n = wid;
  int beg = rp[n], end = rp[n + 1];
  float ad = a_d[n];
  int grp = lane >> 3, l8 = lane & 7;
  int c = l8 * 8;  // valid channels only for l8 < 5
  bool act = l8 < 5;
  float acc[8] = {};
  float psum = 0.f;
  for (int base = beg; base < end; base += 16) {
    int e0 = base + grp;
    int e1 = base + 8 + grp;
    if (e0 < end) {
      int s = csr[e0];
      float x = a_s[s] + ad;
      x = x > 0.f ? x : x * kSlope;
      float p = __expf(x);
      psum += p;
      if (act) {
        half8 hv = *(const half8*)(h + (size_t)s * 40 + c);
#pragma unroll
        for (int j = 0; j < 8; j++) acc[j] += (float)hv[j] * p;
      }
    }
    if (e1 < end) {
      int s = csr[e1];
      float x = a_s[s] + ad;
      x = x > 0.f ? x : x * kSlope;
      float p = __expf(x);
      psum += p;
      if (act) {
        half8 hv = *(const half8*)(h + (size_t)s * 40 + c);
#pragma unroll
        for (int j = 0; j < 8; j++) acc[j] += (float)hv[j] * p;
      }
    }
  }
#pragma unroll
  for (int mask = 8; mask <= 32; mask <<= 1) psum += __shfl_xor(psum, mask, 64);
#pragma unroll
  for (int j = 0; j < 8; j++) {
#pragma unroll
    for (int mask = 8; mask <= 32; mask <<= 1) acc[j] += __shfl_xor(acc[j], mask, 64);
  }
  if (lane < 5) {  // channels 0..39
    float rden = 1.f / (psum + 1e-16f);
    float4 o0, o1;
    o0.x = acc[0] * rden + bias[c + 0];
    o0.y = acc[1] * rden + bias[c + 1];
    o0.z = acc[2] * rden + bias[c + 2];
    o0.w = acc[3] * rden + bias[c + 3];
    o1.x = acc[4] * rden + bias[c + 4];
    o1.y = acc[5] * rden + bias[c + 5];
    o1.z = acc[6] * rden + bias[c + 6];
    o1.w = acc[7] * rden + bias[c + 7];
    *(float4*)(out + (size_t)n * 40 + c) = o0;
    *(float4*)(out + (size_t)n * 40 + c + 4) = o1;
  }
}

// ---------------- driver ----------------

extern "C" void kernel_launch(void* const* d_in, const int* in_sizes, int n_in, void* d_out,
                              int out_size, void* d_ws, size_t ws_size, hipStream_t stream) {
  const float* x = (const float*)d_in[0];
  const int* ei = (const int*)d_in[1];
  const float* W0 = (const float*)d_in[2];
  const float* as0 = (const float*)d_in[3];
  const float* ad0 = (const float*)d_in[4];
  const float* b0 = (const float*)d_in[5];
  const float* bg0 = (const float*)d_in[6];
  const float* bb0 = (const float*)d_in[7];
  const float* bm0 = (const float*)d_in[8];
  const float* bv0 = (const float*)d_in[9];
  const float* W1 = (const float*)d_in[10];
  const float* as1 = (const float*)d_in[11];
  const float* ad1 = (const float*)d_in[12];
  const float* b1 = (const float*)d_in[13];
  const float* bg1 = (const float*)d_in[14];
  const float* bb1 = (const float*)d_in[15];
  const float* bm1 = (const float*)d_in[16];
  const float* bv1 = (const float*)d_in[17];
  const float* W2 = (const float*)d_in[18];
  const float* as2 = (const float*)d_in[19];
  const float* ad2 = (const float*)d_in[20];
  const float* b2 = (const float*)d_in[21];
  float* out = (float*)d_out;

  const int E = in_sizes[1] / 2;
  const int* srcIdx = ei;
  const int* dstIdx = ei + E;

  char* p = (char*)d_ws;
  auto alloc = [&](size_t bytes) -> void* {
    void* r = (void*)p;
    p += (bytes + 255) & ~(size_t)255;
    return r;
  };
  int* rp = (int*)alloc((kN + 1) * sizeof(int));
  int* degcur = (int*)alloc((size_t)2 * kN * sizeof(int));  // deg | cursor
  int* deg = degcur;
  int* cur = degcur + kN;
  int* bsum = (int*)alloc(256 * sizeof(int));
  int* csr = (int*)alloc((size_t)E * sizeof(int));
  float* a_s = (float*)alloc((size_t)kN * 4 * sizeof(float));
  float* a_d = (float*)alloc((size_t)kN * 4 * sizeof(float));
  unsigned short* x16 = (unsigned short*)alloc((size_t)kN * 256 * 2);
  unsigned short* h16 = (unsigned short*)alloc((size_t)kN * 256 * 2);
  unsigned short* act16 = (unsigned short*)alloc((size_t)kN * 256 * 2);
  unsigned short* Wt0 = (unsigned short*)alloc((size_t)256 * 256 * 2);
  unsigned short* Wt1 = (unsigned short*)alloc((size_t)256 * 256 * 2);
  unsigned short* Wt2 = (unsigned short*)alloc((size_t)128 * 256 * 2);

  const int nb = ceil_div(kN, 256);
  const int sblocks = ceil_div(E, 256);

  // CSR build overlapped with prep/GEMM0:
  hipMemsetAsync(degcur, 0, (size_t)2 * kN * sizeof(int), stream);
  k_prep_degree<<<2048, 256, 0, stream>>>(dstIdx, deg, E, x, x16, W0, Wt0, W1, Wt1, W2, Wt2);
  k_scan1<<<nb, 256, 0, stream>>>(deg, rp, bsum, kN);
  k_scan2<<<1, 256, 0, stream>>>(bsum, nb);
  k_scan3<<<nb, 256, 0, stream>>>(rp, bsum, kN);

  const int gemmBlocks = ceil_div(kN, 128) * 2;  // 782
  k_gemm0_scatter<<<gemmBlocks + sblocks, 256, 0, stream>>>(
      x16, Wt0, h16, as0, ad0, a_s, a_d, kN, 256, gemmBlocks, srcIdx, dstIdx, rp, cur, csr, E);

  dim3 gg(ceil_div(kN, 128), 2);
  dim3 gg2(ceil_div(kN, 128), 1);
  int wpn_blocks = ceil_div(kN, 4);

  // Layer 0 aggregation
  k_attn_agg256<<<wpn_blocks, 256, 0, stream>>>(rp, csr, (const _Float16*)h16, a_s, a_d, b0, bg0,
                                                bb0, bm0, bv0, act16, kN);

  // Layer 1
  k_mfma_gemm<<<gg, 256, 0, stream>>>(act16, Wt1, h16, as1, ad1, a_s, a_d, kN, 256, 256, 256, 4,
                                      256);
  k_attn_agg256<<<wpn_blocks, 256, 0, stream>>>(rp, csr, (const _Float16*)h16, a_s, a_d, b1, bg1,
                                                bb1, bm1, bv1, act16, kN);

  // Layer 2: h2 [N,40] packed (row stride 40) in h16
  k_mfma_gemm<<<gg2, 256, 0, stream>>>(act16, Wt2, h16, as2, ad2, a_s, a_d, kN, 256, 40, 40, 1,
                                       40);
  k_attn_agg40<<<wpn_blocks, 256, 0, stream>>>(rp, csr, (const _Float16*)h16, a_s, a_d, b2, out,
                                               kN);
}